// Round 7
// baseline (767.733 us; speedup 1.0000x reference)
//
#include <hip/hip_runtime.h>

#define NV   50000
#define NR   5
#define NT   8
#define CIN  64
#define COUT 64
#define VPB  4
#define BARY (NR*NT*3)      // 120
#define KSTEP 32
#define NICC 10             // (NR*CIN)/KSTEP = 320/32 ic-chunks per j
#define BK_ELEMS (NR*CIN*NT*COUT)   // 320*512 = 163840 per array
#define BM2  64
#define NBLK2 ((NV + BM2 - 1) / BM2)   // 782

#define WL_BYTES 262144
#define WS_NEED  (WL_BYTES + 2u * BK_ELEMS * 2u)   // ~917 KB

typedef __bf16 bf16x8 __attribute__((ext_vector_type(8)));
typedef float  f32x4  __attribute__((ext_vector_type(4)));
typedef unsigned short ushort4v __attribute__((ext_vector_type(4)));

// ---------- K0: kernel -> bf16 hi/lo, [icc][m*64+d][rk] (NO rotation unroll:
// 2x327 KB total, L2-resident; rotation handled by per-wave column offset) ----------
__global__ __launch_bounds__(256) void build_bk(
    const float* __restrict__ kern, unsigned short* __restrict__ bkh,
    unsigned short* __restrict__ bkl)
{
    int e   = blockIdx.x * 256 + threadIdx.x;   // ((icc*512)+(m*64+d))*32+rk
    int rk  = e & 31;
    int md  = (e >> 5) & 511;
    int icc = e >> 14;
    int r   = icc * KSTEP + rk;                 // (i,c) flat
    int i   = r >> 6;
    int c   = r & 63;
    int m   = md >> 6;
    int d   = md & 63;
    float kv = kern[((i * NT + m) * CIN + c) * COUT + d];
    __bf16 h = (__bf16)kv;
    float hf = (float)h;
    __bf16 lo = (__bf16)(kv - hf);
    bkh[e] = __builtin_bit_cast(unsigned short, h);
    bkl[e] = __builtin_bit_cast(unsigned short, lo);
}

// ---------- main v3: j-outer K order, L2-resident B, reg-prefetch B + stage ----------
__global__ __launch_bounds__(512, 2) void geo_mfma3(
    const float* __restrict__ signal,
    const float* __restrict__ bary_w,
    const int*   __restrict__ bary_idx,
    const unsigned short* __restrict__ bkh,
    const unsigned short* __restrict__ bkl,
    float* __restrict__ out,
    int*   __restrict__ wl)
{
    __shared__ __align__(16) unsigned short Ah[2][4][BM2][8];   // 8 KB
    __shared__ __align__(16) unsigned short Al[2][4][BM2][8];   // 8 KB
    __shared__ float nrm[BM2][NT];                              // 2 KB
    __shared__ int   besti[BM2];

    const int tid  = threadIdx.x;
    const int lane = tid & 63;
    const int wn   = tid >> 6;         // wave wn owns rotation k=wn
    const int g    = lane >> 4;
    const int l15  = lane & 15;
    const int vbase = blockIdx.x * BM2;

    // staging mapping: 512 threads = 64 vertices x 8 ch-quads (4 ch each)
    const int vt  = tid >> 3;
    const int cq  = tid & 7;
    const int oct = cq >> 1;
    const int pos = (cq & 1) * 4;

    f32x4 acc[4][4];
    {
        f32x4 z = {0.f, 0.f, 0.f, 0.f};
        #pragma unroll
        for (int mf = 0; mf < 4; ++mf)
            #pragma unroll
            for (int nf = 0; nf < 4; ++nf) acc[mf][nf] = z;
    }

    // ---- stage-load registers (live across MFMA: issue-early, write-late) ----
    float4 sp, sq, sr;
    float  sw0, sw1, sw2;
    bool   sv_ok = false;

    auto SLOAD = [&](int j, int icc) {
        const int i  = icc >> 1;
        const int c0 = (icc & 1) * 32;
        const int v  = vbase + vt;
        sv_ok = (v < NV);
        if (sv_ok) {
            const int base = v * BARY + (i * NT + j) * 3;
            sw0 = bary_w[base + 0];
            sw1 = bary_w[base + 1];
            sw2 = bary_w[base + 2];
            const int i0 = bary_idx[base + 0];
            const int i1 = bary_idx[base + 1];
            const int i2 = bary_idx[base + 2];
            const int ch = c0 + cq * 4;
            sp = *(const float4*)(signal + i0 * CIN + ch);
            sq = *(const float4*)(signal + i1 * CIN + ch);
            sr = *(const float4*)(signal + i2 * CIN + ch);
        }
    };
    auto SWRITE = [&](int b) {
        float xv[4];
        if (sv_ok) {
            xv[0] = sw0 * sp.x + sw1 * sq.x + sw2 * sr.x;
            xv[1] = sw0 * sp.y + sw1 * sq.y + sw2 * sr.y;
            xv[2] = sw0 * sp.z + sw1 * sq.z + sw2 * sr.z;
            xv[3] = sw0 * sp.w + sw1 * sq.w + sw2 * sr.w;
        } else {
            xv[0] = xv[1] = xv[2] = xv[3] = 0.f;
        }
        ushort4v hv, lv;
        #pragma unroll
        for (int e = 0; e < 4; ++e) {
            __bf16 h  = (__bf16)xv[e];
            float  hf = (float)h;
            __bf16 lo = (__bf16)(xv[e] - hf);
            hv[e] = __builtin_bit_cast(unsigned short, h);
            lv[e] = __builtin_bit_cast(unsigned short, lo);
        }
        *(ushort4v*)&Ah[b][oct][vt][pos] = hv;
        *(ushort4v*)&Al[b][oct][vt][pos] = lv;
    };

    // ---- B fragment loads (L2-resident 655 KB footprint) ----
    bf16x8 bhc[4], blc[4], bhn[4], bln[4];
    auto BLOAD = [&](int j, int icc, bf16x8* bh, bf16x8* bl) {
        const int m = (j + wn) & 7;
        #pragma unroll
        for (int nf = 0; nf < 4; ++nf) {
            const int col  = m * 64 + nf * 16 + l15;
            const int base = (icc * 512 + col) * KSTEP + g * 8;
            bh[nf] = *(const bf16x8*)(bkh + base);
            bl[nf] = *(const bf16x8*)(bkl + base);
        }
    };

    // ---- prologue: stage it=0 into buf0; preload B for it=0 ----
    SLOAD(0, 0);
    SWRITE(0);
    __syncthreads();
    BLOAD(0, 0, bhc, blc);

    int it = 0;
    for (int j = 0; j < NT; ++j) {
        for (int icc = 0; icc < NICC; ++icc, ++it) {
            const int b = it & 1;

            // A fragments for this chunk (written by previous iteration)
            bf16x8 ah[4], al[4];
            #pragma unroll
            for (int mf = 0; mf < 4; ++mf) {
                ah[mf] = *(const bf16x8*)&Ah[b][g][mf * 16 + l15][0];
                al[mf] = *(const bf16x8*)&Al[b][g][mf * 16 + l15][0];
            }

            // issue next-chunk loads EARLY (hidden under the MFMA block)
            const int  iccn = (icc == NICC - 1) ? 0 : icc + 1;
            const int  jn   = (icc == NICC - 1) ? j + 1 : j;
            const bool have_next = (jn < NT);
            if (have_next) {
                SLOAD(jn, iccn);
                BLOAD(jn, iccn, bhn, bln);
            }

            // 48 MFMAs (~931 SIMD-cycles of matrix-pipe time per wave)
            #pragma unroll
            for (int nf = 0; nf < 4; ++nf) {
                #pragma unroll
                for (int mf = 0; mf < 4; ++mf) {
                    acc[mf][nf] = __builtin_amdgcn_mfma_f32_16x16x32_bf16(ah[mf], bhc[nf], acc[mf][nf], 0, 0, 0);
                    acc[mf][nf] = __builtin_amdgcn_mfma_f32_16x16x32_bf16(ah[mf], blc[nf], acc[mf][nf], 0, 0, 0);
                    acc[mf][nf] = __builtin_amdgcn_mfma_f32_16x16x32_bf16(al[mf], bhc[nf], acc[mf][nf], 0, 0, 0);
                }
            }

            if (have_next) {
                SWRITE(b ^ 1);      // convert + LDS write (waits stage loads)
                #pragma unroll
                for (int nf = 0; nf < 4; ++nf) { bhc[nf] = bhn[nf]; blc[nf] = bln[nf]; }
            }
            __syncthreads();
        }
    }

    // ---- epilogue: wave wn owns rotation wn; norms per row ----
    #pragma unroll
    for (int mf = 0; mf < 4; ++mf)
        #pragma unroll
        for (int ri = 0; ri < 4; ++ri) {
            float s = 0.f;
            #pragma unroll
            for (int nf = 0; nf < 4; ++nf) {
                float vv = acc[mf][nf][ri];
                s = fmaf(vv, vv, s);
            }
            #pragma unroll
            for (int off = 1; off < 16; off <<= 1)
                s += __shfl_xor(s, off);
            if (l15 == 0) nrm[mf * 16 + g * 4 + ri][wn] = s;
        }
    __syncthreads();

    if (tid < BM2) {
        const int v = vbase + tid;
        float bn = nrm[tid][0];
        float sec = -1e30f;
        int best = 0;
        #pragma unroll
        for (int k = 1; k < NT; ++k) {
            float nv = nrm[tid][k];
            if (nv > bn)       { sec = bn; bn = nv; best = k; }
            else if (nv > sec) { sec = nv; }
        }
        const bool flag = (bn - sec) <= (2e-3f + 4e-5f * bn);
        besti[tid] = flag ? -1 : best;
        if (flag && v < NV) { int p = atomicAdd(wl, 1); wl[1 + p] = v; }
    }
    __syncthreads();

    #pragma unroll
    for (int mf = 0; mf < 4; ++mf)
        #pragma unroll
        for (int ri = 0; ri < 4; ++ri) {
            const int row = mf * 16 + g * 4 + ri;
            const int v   = vbase + row;
            const int bsel = (v < NV) ? besti[row] : -1;
            if (bsel == wn) {
                #pragma unroll
                for (int nf = 0; nf < 4; ++nf) {
                    const int d = nf * 16 + l15;
                    out[v * COUT + d] = fmaxf(acc[mf][nf][ri], 0.0f);
                }
            }
        }
}

// ---------- fp64 refine for flagged vertices (also full fallback) ----------
__global__ __launch_bounds__(256) void geo_refine_f64(
    const float* __restrict__ signal,
    const float* __restrict__ bary_w,
    const int*   __restrict__ bary_idx,
    const float* __restrict__ kern,
    float*       __restrict__ out,
    const int*   __restrict__ wl,
    int nall)
{
    __shared__ __align__(16) float xs[4][NR][CIN][NT];
    const int wave = threadIdx.x >> 6;
    const int lane = threadIdx.x & 63;
    const int count = wl ? wl[0] : nall;
    const int nw = gridDim.x * 4;

    for (int w = blockIdx.x * 4 + wave; w < count; w += nw) {
        const int v = wl ? wl[1 + w] : w;
        for (int ij = 0; ij < NR * NT; ++ij) {
            int i = ij >> 3, j = ij & 7;
            int base = v * BARY + ij * 3;
            float w0 = bary_w[base], w1 = bary_w[base+1], w2 = bary_w[base+2];
            int   i0 = bary_idx[base], i1 = bary_idx[base+1], i2 = bary_idx[base+2];
            xs[wave][i][lane][j] = w0 * signal[i0*CIN + lane]
                                 + w1 * signal[i1*CIN + lane]
                                 + w2 * signal[i2*CIN + lane];
        }
        double acc[NT];
        #pragma unroll
        for (int k = 0; k < NT; ++k) acc[k] = 0.0;
        for (int i = 0; i < NR; ++i) {
            const float* __restrict__ Ki = kern + i * (NT * CIN * COUT);
            for (int c = 0; c < CIN; ++c) {
                float4 xa = *reinterpret_cast<const float4*>(&xs[wave][i][c][0]);
                float4 xb = *reinterpret_cast<const float4*>(&xs[wave][i][c][4]);
                double x8[NT] = {(double)xa.x, (double)xa.y, (double)xa.z, (double)xa.w,
                                 (double)xb.x, (double)xb.y, (double)xb.z, (double)xb.w};
                #pragma unroll
                for (int m = 0; m < NT; ++m) {
                    double kv = (double)Ki[(m * CIN + c) * COUT + lane];
                    #pragma unroll
                    for (int k = 0; k < NT; ++k)
                        acc[k] = fma(x8[(m - k + NT) & (NT - 1)], kv, acc[k]);
                }
            }
        }
        double nk[NT];
        #pragma unroll
        for (int k = 0; k < NT; ++k) {
            double n = acc[k] * acc[k];
            #pragma unroll
            for (int off = 32; off >= 1; off >>= 1) n += __shfl_xor(n, off);
            nk[k] = n;
        }
        int best = 0; double bn = nk[0];
        #pragma unroll
        for (int k = 1; k < NT; ++k)
            if (nk[k] > bn) { bn = nk[k]; best = k; }
        double sel = acc[0];
        #pragma unroll
        for (int k = 1; k < NT; ++k) sel = (best == k) ? acc[k] : sel;
        out[v * COUT + lane] = fmaxf((float)sel, 0.0f);
    }
}

// ---------- round-3 fp32 two-pass fallback (ws too small for Bk) ----------
__global__ __launch_bounds__(256) void geo_conv_f32(
    const float* __restrict__ signal,
    const float* __restrict__ bary_w,
    const int*   __restrict__ bary_idx,
    const float* __restrict__ kern,
    float*       __restrict__ out,
    int*         __restrict__ wl)
{
    __shared__ __align__(16) float xs[VPB][NR][CIN][NT];
    __shared__ float wsh[VPB][BARY];
    __shared__ int   ish[VPB][BARY];

    const int tid   = threadIdx.x;
    const int wave  = tid >> 6;
    const int lane  = tid & 63;
    const int vbase = blockIdx.x * VPB;

    for (int e = tid; e < VPB * BARY; e += 256) {
        int s = e / BARY, r = e - s * BARY;
        wsh[s][r] = bary_w[(vbase + s) * BARY + r];
        ish[s][r] = bary_idx[(vbase + s) * BARY + r];
    }
    __syncthreads();
    {
        const int s = wave;
        for (int ij = 0; ij < NR * NT; ++ij) {
            int i = ij >> 3, j = ij & 7;
            float w0 = wsh[s][ij*3], w1 = wsh[s][ij*3+1], w2 = wsh[s][ij*3+2];
            int   i0 = ish[s][ij*3], i1 = ish[s][ij*3+1], i2 = ish[s][ij*3+2];
            xs[s][i][lane][j] = w0 * signal[i0*CIN + lane]
                              + w1 * signal[i1*CIN + lane]
                              + w2 * signal[i2*CIN + lane];
        }
    }
    __syncthreads();

    float acc[NT];
    #pragma unroll
    for (int k = 0; k < NT; ++k) acc[k] = 0.0f;
    const int s = wave, d = lane;
    for (int i = 0; i < NR; ++i) {
        const float* __restrict__ Ki = kern + i * (NT * CIN * COUT);
        for (int c = 0; c < CIN; ++c) {
            float4 xa = *reinterpret_cast<const float4*>(&xs[s][i][c][0]);
            float4 xb = *reinterpret_cast<const float4*>(&xs[s][i][c][4]);
            float x8[NT] = {xa.x, xa.y, xa.z, xa.w, xb.x, xb.y, xb.z, xb.w};
            #pragma unroll
            for (int m = 0; m < NT; ++m) {
                float kv = Ki[(m * CIN + c) * COUT + d];
                #pragma unroll
                for (int k = 0; k < NT; ++k)
                    acc[k] = fmaf(x8[(m - k + NT) & (NT - 1)], kv, acc[k]);
            }
        }
    }
    double nk[NT];
    #pragma unroll
    for (int k = 0; k < NT; ++k) {
        double n = (double)acc[k] * (double)acc[k];
        #pragma unroll
        for (int off = 32; off >= 1; off >>= 1) n += __shfl_xor(n, off);
        nk[k] = n;
    }
    int best = 0; double bn = nk[0], sec = -1.0e300;
    #pragma unroll
    for (int k = 1; k < NT; ++k) {
        if (nk[k] > bn)       { sec = bn; bn = nk[k]; best = k; }
        else if (nk[k] > sec) { sec = nk[k]; }
    }
    const int v = vbase + s;
    if (bn - sec <= 4.0e-3 + 3.0e-5 * bn) {
        if (lane == 0) { int pos = atomicAdd(wl, 1); wl[1 + pos] = v; }
    } else {
        float sel = acc[0];
        #pragma unroll
        for (int k = 1; k < NT; ++k) sel = (best == k) ? acc[k] : sel;
        out[v * COUT + d] = fmaxf(sel, 0.0f);
    }
}

extern "C" void kernel_launch(void* const* d_in, const int* in_sizes, int n_in,
                              void* d_out, int out_size, void* d_ws, size_t ws_size,
                              hipStream_t stream) {
    const float* signal   = (const float*)d_in[0];
    const float* bary_w   = (const float*)d_in[1];
    const int*   bary_idx = (const int*)d_in[2];
    const float* kern     = (const float*)d_in[3];
    float* out = (float*)d_out;

    if (ws_size >= (size_t)WS_NEED) {
        int* wl = (int*)d_ws;
        unsigned short* bkh = (unsigned short*)((char*)d_ws + WL_BYTES);
        unsigned short* bkl = bkh + BK_ELEMS;
        hipMemsetAsync(wl, 0, sizeof(int), stream);
        build_bk<<<dim3(BK_ELEMS / 256), dim3(256), 0, stream>>>(kern, bkh, bkl);
        geo_mfma3<<<dim3(NBLK2), dim3(512), 0, stream>>>(
            signal, bary_w, bary_idx, bkh, bkl, out, wl);
        geo_refine_f64<<<dim3(128), dim3(256), 0, stream>>>(
            signal, bary_w, bary_idx, kern, out, wl, 0);
    } else if (ws_size >= (size_t)(1 + NV) * sizeof(int)) {
        int* wl = (int*)d_ws;
        hipMemsetAsync(wl, 0, sizeof(int), stream);
        geo_conv_f32<<<dim3(NV / VPB), dim3(256), 0, stream>>>(
            signal, bary_w, bary_idx, kern, out, wl);
        geo_refine_f64<<<dim3(128), dim3(256), 0, stream>>>(
            signal, bary_w, bary_idx, kern, out, wl, 0);
    } else {
        geo_refine_f64<<<dim3(256), dim3(256), 0, stream>>>(
            signal, bary_w, bary_idx, kern, out, nullptr, NV);
    }
}